// Round 1
// 947.190 us; speedup vs baseline: 3.4303x; 3.4303x over previous
//
#include <hip/hip_runtime.h>

#define DEVINL __device__ __forceinline__

constexpr int N_SITES = 500000;
constexpr int C1 = 128;
constexpr int CH = 64;
constexpr int C2 = 128;
constexpr float BN_EPS = 1e-5f;
constexpr int NT32 = N_SITES / 32;   // 15625 tiles of 32 sites (exact)

typedef __attribute__((ext_vector_type(4))) float f32x4;
typedef __attribute__((ext_vector_type(8))) short s16x8;

DEVINL float bf2f(unsigned short s) { return __uint_as_float(((unsigned)s) << 16); }
DEVINL unsigned short f2bf(float f) {
  unsigned u = __float_as_uint(f);
  return (unsigned short)((u + 0x7fffu + ((u >> 16) & 1u)) >> 16);  // RNE
}
DEVINL float silu_f(float x) { return x / (1.0f + __expf(-x)); }

template<bool F32>
DEVINL float rdf(const void* p, long i) {
  if constexpr (F32) return ((const float*)p)[i];
  else return bf2f(((const unsigned short*)p)[i]);
}

DEVINL bool probe_f32(const void* buf) {
  unsigned w = ((const unsigned*)buf)[threadIdx.x & 63];
  unsigned e = (w >> 7) & 0xFFu;
  bool bf_like = (e >= 90u && e <= 134u) || ((w & 0xFFFFu) == 0u);
  return __popcll(__ballot(bf_like)) < 48;
}
DEVINL bool probe_i64(const int* nbr) {
  int v = nbr[2 * (threadIdx.x & 63) + 1];
  return __popcll(__ballot(v == 0)) == 64;
}
template<bool I64>
DEVINL int rd_idx(const int* nbr, long ofs) {
  if constexpr (I64) return nbr[2 * ofs];
  else return nbr[ofs];
}

DEVINL s16x8 as_s16x8(uint4 v) { union { uint4 u; s16x8 s; } c; c.u = v; return c.s; }

DEVINL s16x8 pack8(float a0, float a1, float a2, float a3,
                   float a4, float a5, float a6, float a7) {
  uint4 r;
  r.x = (unsigned)f2bf(a0) | ((unsigned)f2bf(a1) << 16);
  r.y = (unsigned)f2bf(a2) | ((unsigned)f2bf(a3) << 16);
  r.z = (unsigned)f2bf(a4) | ((unsigned)f2bf(a5) << 16);
  r.w = (unsigned)f2bf(a6) | ((unsigned)f2bf(a7) << 16);
  return as_s16x8(r);
}

DEVINL f32x4 mfma16(s16x8 a, s16x8 b, f32x4 c) {
  return __builtin_amdgcn_mfma_f32_16x16x32_bf16(a, b, c, 0, 0, 0);
}

// ---------------------------------------------------------------------------
// K1: h = silu(bn1(features @ W1)), h bf16 [N][64].
// MFMA 16x16x32: per wave, 32-site x 64-ch tile (2 row-tiles x 4 n-tiles, K=128).
// W1 B-fragments live in registers (reused across all tiles).
// ---------------------------------------------------------------------------
template<bool F32>
DEVINL void cv1_body(const void* feat, const void* W1,
                     const void* g1, const void* b1, const void* m1, const void* v1,
                     unsigned short* __restrict__ h)
{
  const int tid = threadIdx.x;
  const int lane = tid & 63, w = tid >> 6;
  const int lr = lane & 15;   // A row / D col
  const int lg = lane >> 4;   // k-group / D row-group

  // B-fragments of W1: B[k][n], k = kk*32 + lg*8 + j, n = nt*16 + lr
  s16x8 bw[4][4];
#pragma unroll
  for (int kk = 0; kk < 4; ++kk)
#pragma unroll
    for (int nt = 0; nt < 4; ++nt) {
      float e[8];
#pragma unroll
      for (int j = 0; j < 8; ++j)
        e[j] = rdf<F32>(W1, (long)(kk * 32 + lg * 8 + j) * CH + nt * 16 + lr);
      bw[kk][nt] = pack8(e[0], e[1], e[2], e[3], e[4], e[5], e[6], e[7]);
    }
  float s1v[4], t1v[4];
#pragma unroll
  for (int nt = 0; nt < 4; ++nt) {
    int c = nt * 16 + lr;
    s1v[nt] = rdf<F32>(g1, c) * rsqrtf(rdf<F32>(v1, c) + BN_EPS);
    t1v[nt] = rdf<F32>(b1, c) - rdf<F32>(m1, c) * s1v[nt];
  }

  const int nw = gridDim.x * 4;
  for (int tile = blockIdx.x * 4 + w; tile < NT32; tile += nw) {
    const long base = (long)tile * 32;
    f32x4 acc[2][4];
#pragma unroll
    for (int r = 0; r < 2; ++r)
#pragma unroll
      for (int nt = 0; nt < 4; ++nt) acc[r][nt] = (f32x4)0.0f;

#pragma unroll
    for (int r = 0; r < 2; ++r) {
      const long row = base + r * 16 + lr;
#pragma unroll
      for (int kk = 0; kk < 4; ++kk) {
        s16x8 a;
        if constexpr (F32) {
          const float* fp = (const float*)feat + row * C1 + kk * 32 + lg * 8;
          float4 f0 = ((const float4*)fp)[0];
          float4 f1 = ((const float4*)fp)[1];
          a = pack8(f0.x, f0.y, f0.z, f0.w, f1.x, f1.y, f1.z, f1.w);
        } else {
          a = as_s16x8(*(const uint4*)((const unsigned short*)feat + row * C1 + kk * 32 + lg * 8));
        }
#pragma unroll
        for (int nt = 0; nt < 4; ++nt)
          acc[r][nt] = mfma16(a, bw[kk][nt], acc[r][nt]);
      }
    }
    // epilogue: BN1 + SiLU, bf16 store.  D: row = lg*4 + q, col = lr.
#pragma unroll
    for (int r = 0; r < 2; ++r)
#pragma unroll
      for (int nt = 0; nt < 4; ++nt)
#pragma unroll
        for (int q = 0; q < 4; ++q) {
          long site = base + r * 16 + lg * 4 + q;
          int ch = nt * 16 + lr;
          float vv = acc[r][nt][q] * s1v[nt] + t1v[nt];
          h[(size_t)site * CH + ch] = f2bf(silu_f(vv));
        }
  }
}

__global__ __launch_bounds__(256, 2) void k_cv1(
    const void* feat, const void* W1,
    const void* g1, const void* b1, const void* m1, const void* v1,
    unsigned short* __restrict__ h, unsigned short* __restrict__ zrow)
{
  // zero sentinel row (parked at start of d_out; consumed by k_cv2, overwritten by k_cv3)
  if (blockIdx.x == 0 && threadIdx.x < 8)
    ((uint4*)zrow)[threadIdx.x] = make_uint4(0u, 0u, 0u, 0u);
  if (probe_f32(feat)) cv1_body<true >(feat, W1, g1, b1, m1, v1, h);
  else                 cv1_body<false>(feat, W1, g1, b1, m1, v1, h);
}

// ---------------------------------------------------------------------------
// K2: t = silu(bn2( sum_{k=0..8} gather(h, nbr[k]) @ W2[k] )), t bf16 [N][64].
// All 9 taps fused; W2 staged in LDS in MFMA B-fragment order:
//   lw2[((tap*2+kk)*4+nt)*64 + lane][8]  -> one ds_read_b128 per fragment.
// Gather IS the A-fragment load: lane reads 16B of h[nbr_row(lr)] at k-offset.
// Sentinel (row==N) redirects to the 128B zero row.
// ---------------------------------------------------------------------------
template<bool F32, bool I64>
DEVINL void cv2_body(const unsigned short* __restrict__ h, const int* __restrict__ nbr,
                     const void* W2,
                     const void* g2, const void* b2, const void* m2, const void* v2,
                     unsigned short* __restrict__ t,
                     const unsigned short* __restrict__ zrow,
                     unsigned short* lw2)
{
  const int tid = threadIdx.x;
  const int lane = tid & 63, w = tid >> 6;
  const int lr = lane & 15, lg = lane >> 4;

  // stage W2 -> LDS fragment order
  for (int idx = tid; idx < 9 * 64 * 64; idx += 256) {
    int tap = idx >> 12;
    int k = (idx >> 6) & 63, n = idx & 63;
    int kk = k >> 5, g = (k >> 3) & 3, j = k & 7, nt = n >> 4;
    int ln = (n & 15) | (g << 4);
    lw2[((((tap * 2 + kk) * 4 + nt) * 64) + ln) * 8 + j] = f2bf(rdf<F32>(W2, (long)idx));
  }
  float s2v[4], t2v[4];
#pragma unroll
  for (int nt = 0; nt < 4; ++nt) {
    int c = nt * 16 + lr;
    s2v[nt] = rdf<F32>(g2, c) * rsqrtf(rdf<F32>(v2, c) + BN_EPS);
    t2v[nt] = rdf<F32>(b2, c) - rdf<F32>(m2, c) * s2v[nt];
  }
  __syncthreads();

  const s16x8* lw2s = (const s16x8*)lw2;
  const int nw = gridDim.x * 4;
  for (int tile = blockIdx.x * 4 + w; tile < NT32; tile += nw) {
    const long base = (long)tile * 32;
    f32x4 acc[2][4];
#pragma unroll
    for (int r = 0; r < 2; ++r)
#pragma unroll
      for (int nt = 0; nt < 4; ++nt) acc[r][nt] = (f32x4)0.0f;

#pragma unroll
    for (int tap = 0; tap < 9; ++tap) {
      int r0 = rd_idx<I64>(nbr, (long)tap * N_SITES + base + lr);
      int r1 = rd_idx<I64>(nbr, (long)tap * N_SITES + base + 16 + lr);
      const unsigned short* s0 = (r0 == N_SITES) ? zrow : h + (size_t)r0 * CH;
      const unsigned short* s1 = (r1 == N_SITES) ? zrow : h + (size_t)r1 * CH;
      s16x8 a00 = as_s16x8(*(const uint4*)(s0 + lg * 8));        // kk=0
      s16x8 a01 = as_s16x8(*(const uint4*)(s0 + 32 + lg * 8));   // kk=1
      s16x8 a10 = as_s16x8(*(const uint4*)(s1 + lg * 8));
      s16x8 a11 = as_s16x8(*(const uint4*)(s1 + 32 + lg * 8));
#pragma unroll
      for (int nt = 0; nt < 4; ++nt) {
        s16x8 b0 = lw2s[((tap * 2 + 0) * 4 + nt) * 64 + lane];
        s16x8 b1 = lw2s[((tap * 2 + 1) * 4 + nt) * 64 + lane];
        acc[0][nt] = mfma16(a00, b0, acc[0][nt]);
        acc[1][nt] = mfma16(a10, b0, acc[1][nt]);
        acc[0][nt] = mfma16(a01, b1, acc[0][nt]);
        acc[1][nt] = mfma16(a11, b1, acc[1][nt]);
      }
    }
#pragma unroll
    for (int r = 0; r < 2; ++r)
#pragma unroll
      for (int nt = 0; nt < 4; ++nt)
#pragma unroll
        for (int q = 0; q < 4; ++q) {
          long site = base + r * 16 + lg * 4 + q;
          int ch = nt * 16 + lr;
          t[(size_t)site * CH + ch] = f2bf(silu_f(acc[r][nt][q] * s2v[nt] + t2v[nt]));
        }
  }
}

__global__ __launch_bounds__(256, 2) void k_cv2(
    const unsigned short* __restrict__ h, const int* __restrict__ nbr,
    const void* W2,
    const void* g2, const void* b2, const void* m2, const void* v2,
    unsigned short* __restrict__ t, const unsigned short* __restrict__ zrow)
{
  __shared__ __align__(16) unsigned short lw2[9 * 8 * 64 * 8];  // 73728 B
  bool f32 = probe_f32(W2);
  bool i64 = probe_i64(nbr);
  if (f32) { if (i64) cv2_body<true , true >(h, nbr, W2, g2, b2, m2, v2, t, zrow, lw2);
             else     cv2_body<true , false>(h, nbr, W2, g2, b2, m2, v2, t, zrow, lw2); }
  else     { if (i64) cv2_body<false, true >(h, nbr, W2, g2, b2, m2, v2, t, zrow, lw2);
             else     cv2_body<false, false>(h, nbr, W2, g2, b2, m2, v2, t, zrow, lw2); }
}

// ---------------------------------------------------------------------------
// K3: out = silu( bn3(t @ W3) + features ).  W3 B-fragments in registers.
// ---------------------------------------------------------------------------
template<bool F32>
DEVINL void cv3_body(const unsigned short* __restrict__ t, const void* W3,
                     const void* feat,
                     const void* g3, const void* b3, const void* m3, const void* v3,
                     void* out)
{
  const int tid = threadIdx.x;
  const int lane = tid & 63, w = tid >> 6;
  const int lr = lane & 15, lg = lane >> 4;

  s16x8 bw[2][8];
#pragma unroll
  for (int kk = 0; kk < 2; ++kk)
#pragma unroll
    for (int nt = 0; nt < 8; ++nt) {
      float e[8];
#pragma unroll
      for (int j = 0; j < 8; ++j)
        e[j] = rdf<F32>(W3, (long)(kk * 32 + lg * 8 + j) * C2 + nt * 16 + lr);
      bw[kk][nt] = pack8(e[0], e[1], e[2], e[3], e[4], e[5], e[6], e[7]);
    }
  float s3v[8], t3v[8];
#pragma unroll
  for (int nt = 0; nt < 8; ++nt) {
    int c = nt * 16 + lr;
    s3v[nt] = rdf<F32>(g3, c) * rsqrtf(rdf<F32>(v3, c) + BN_EPS);
    t3v[nt] = rdf<F32>(b3, c) - rdf<F32>(m3, c) * s3v[nt];
  }

  const int nw = gridDim.x * 4;
  for (int tile = blockIdx.x * 4 + w; tile < NT32; tile += nw) {
    const long base = (long)tile * 32;
    f32x4 acc[2][8];
#pragma unroll
    for (int r = 0; r < 2; ++r)
#pragma unroll
      for (int nt = 0; nt < 8; ++nt) acc[r][nt] = (f32x4)0.0f;

#pragma unroll
    for (int r = 0; r < 2; ++r) {
      const size_t row = (size_t)(base + r * 16 + lr);
#pragma unroll
      for (int kk = 0; kk < 2; ++kk) {
        s16x8 a = as_s16x8(*(const uint4*)(t + row * CH + kk * 32 + lg * 8));
#pragma unroll
        for (int nt = 0; nt < 8; ++nt)
          acc[r][nt] = mfma16(a, bw[kk][nt], acc[r][nt]);
      }
    }
#pragma unroll
    for (int r = 0; r < 2; ++r)
#pragma unroll
      for (int nt = 0; nt < 8; ++nt)
#pragma unroll
        for (int q = 0; q < 4; ++q) {
          long site = base + r * 16 + lg * 4 + q;
          int ch = nt * 16 + lr;
          float o = acc[r][nt][q] * s3v[nt] + t3v[nt];
          float fv = rdf<F32>(feat, (long)site * C1 + ch);
          float res = silu_f(o + fv);
          if constexpr (F32) ((float*)out)[(size_t)site * C2 + ch] = res;
          else ((unsigned short*)out)[(size_t)site * C2 + ch] = f2bf(res);
        }
  }
}

__global__ __launch_bounds__(256, 2) void k_cv3(
    const unsigned short* __restrict__ t, const void* W3, const void* feat,
    const void* g3, const void* b3, const void* m3, const void* v3,
    void* out)
{
  if (probe_f32(feat)) cv3_body<true >(t, W3, feat, g3, b3, m3, v3, out);
  else                 cv3_body<false>(t, W3, feat, g3, b3, m3, v3, out);
}

// ---------------------------------------------------------------------------
extern "C" void kernel_launch(void* const* d_in, const int* in_sizes, int n_in,
                              void* d_out, int out_size, void* d_ws, size_t ws_size,
                              hipStream_t stream)
{
  (void)out_size; (void)ws_size;
  // dict order: feat(64e6B) nbr(4.5e6 elems) W1 W2 W3 g1 b1 m1 v1 g2 b2 m2 v2 g3 b3 m3 v3
  int mp[17];
  for (int i = 0; i < 17; ++i) mp[i] = i;
  if (n_in == 17 && in_sizes[0] != 64000000 &&
      in_sizes[6] == 64000000 && in_sizes[13] == 4500000) {
    const int amap[17] = {6, 13, 0, 1, 2, 7, 3, 10, 14, 8, 4, 11, 15, 9, 5, 12, 16};
    for (int i = 0; i < 17; ++i) mp[i] = amap[i];
  }
  const void* feat = d_in[mp[0]];
  const int*  nbr  = (const int*)d_in[mp[1]];
  const void* W1 = d_in[mp[2]];
  const void* W2 = d_in[mp[3]];
  const void* W3 = d_in[mp[4]];
  const void* g1 = d_in[mp[5]],  *b1 = d_in[mp[6]],  *m1 = d_in[mp[7]],  *v1 = d_in[mp[8]];
  const void* g2 = d_in[mp[9]],  *b2 = d_in[mp[10]], *m2 = d_in[mp[11]], *v2 = d_in[mp[12]];
  const void* g3 = d_in[mp[13]], *b3 = d_in[mp[14]], *m3 = d_in[mp[15]], *v3 = d_in[mp[16]];

  // workspace: h = N*64 bf16 (64,000,000 B), t = N*64 bf16 (64,000,000 B)
  unsigned short* h = (unsigned short*)d_ws;
  unsigned short* t = (unsigned short*)((char*)d_ws + (size_t)N_SITES * CH * 2);
  // 128B zero row for sentinel gathers lives at the start of d_out:
  // zeroed by k_cv1, read by k_cv2, overwritten by k_cv3.
  unsigned short* zrow = (unsigned short*)d_out;

  k_cv1<<<1024, 256, 0, stream>>>(feat, W1, g1, b1, m1, v1, h, zrow);
  k_cv2<<<512, 256, 0, stream>>>(h, nbr, W2, g2, b2, m2, v2, t, zrow);
  k_cv3<<<1024, 256, 0, stream>>>(t, W3, feat, g3, b3, m3, v3, (void*)d_out);
}